// Round 2
// baseline (1356.508 us; speedup 1.0000x reference)
//
#include <hip/hip_runtime.h>
#include <stdint.h>

typedef __attribute__((ext_vector_type(4))) float f32x4;
typedef __attribute__((ext_vector_type(8))) short short8;
typedef __attribute__((ext_vector_type(4))) short short4v;

#define CDIV(a, b) (((a) + (b) - 1) / (b))

__device__ __forceinline__ unsigned short f2bf(float x) {
  union { float f; unsigned int u; } c; c.f = x;
  unsigned int r = c.u + 0x7FFFu + ((c.u >> 16) & 1u);   // round-to-nearest-even
  return (unsigned short)(r >> 16);
}
__device__ __forceinline__ float bf2f(unsigned short b) {
  union { unsigned int u; float f; } c; c.u = (unsigned int)b << 16; return c.f;
}

// ---------------- weight transpose: W[K][N] f32 -> Wt[N][Kpad] bf16, zero-padded ----------------
__global__ void transpose_w(const float* __restrict__ W, unsigned short* __restrict__ Wt,
                            int K, int N, int Kpad) {
  __shared__ float tile[32][33];
  int kb = blockIdx.x * 32, nb = blockIdx.y * 32;
  int tx = threadIdx.x & 31, ty = threadIdx.x >> 5;  // 256 threads = 32x8
  for (int r = ty; r < 32; r += 8) {
    int k = kb + r, n = nb + tx;
    tile[r][tx] = (k < K && n < N) ? W[(size_t)k * N + n] : 0.f;
  }
  __syncthreads();
  for (int r = ty; r < 32; r += 8) {
    int n = nb + r, k = kb + tx;
    if (n < N && k < Kpad) Wt[(size_t)n * Kpad + k] = f2bf(tile[tx][r]);
  }
}

// ---------------- graph prep ----------------
__global__ void zero_i32(int* __restrict__ p, int n) {
  int i = blockIdx.x * blockDim.x + threadIdx.x;
  if (i < n) p[i] = 0;
}

__global__ void deg_init(int* __restrict__ a, int* __restrict__ b, int n) {
  int i = blockIdx.x * blockDim.x + threadIdx.x;
  if (i < n) { a[i] = 1; b[i] = 1; }   // self-loop
}

// edge index arrives as int32 (harness converts integer inputs to int32)
__global__ void deg_hist(const int* __restrict__ ei, int E, int* __restrict__ deg, int n) {
  int e = blockIdx.x * blockDim.x + threadIdx.x;
  if (e >= E) return;
  unsigned int d = (unsigned int)ei[(size_t)E + e];
  if (d < (unsigned int)n) atomicAdd(&deg[d], 1);
}

__global__ void dinv_k(const int* __restrict__ deg, float* __restrict__ dinv, int n) {
  int i = blockIdx.x * blockDim.x + threadIdx.x;
  if (i < n) dinv[i] = rsqrtf((float)deg[i]);
}

// exclusive scan of (deg-1) -> row_ptr[0..n], single block of 1024, shfl-based
__global__ void scan_rowptr(const int* __restrict__ deg, int* __restrict__ rp, int n) {
  __shared__ int wsum[16];
  __shared__ int carry_s;
  const int tid = threadIdx.x, lane = tid & 63, w = tid >> 6;
  if (tid == 0) carry_s = 0;
  __syncthreads();
  for (int base = 0; base < n; base += 1024) {
    int i = base + tid;
    int d = (i < n) ? (deg[i] - 1) : 0;
    int v = d;
    #pragma unroll
    for (int off = 1; off < 64; off <<= 1) {
      int t = __shfl_up(v, off, 64);
      if (lane >= off) v += t;
    }
    if (lane == 63) wsum[w] = v;
    __syncthreads();
    int carry = carry_s;
    if (w == 0) {
      int s = (lane < 16) ? wsum[lane] : 0;
      #pragma unroll
      for (int off = 1; off < 16; off <<= 1) {
        int t = __shfl_up(s, off, 64);
        if (lane >= off) s += t;
      }
      if (lane < 16) wsum[lane] = s;
    }
    __syncthreads();
    int woff = (w > 0) ? wsum[w - 1] : 0;
    if (i < n) rp[i] = carry + woff + v - d;
    if (tid == 0) carry_s = carry + wsum[15];
    __syncthreads();
  }
  if (threadIdx.x == 0) rp[n] = carry_s;
}

__global__ void csr_fill(const int* __restrict__ ei, int E,
                         const int* __restrict__ row_ptr, int* __restrict__ cursor,
                         const float* __restrict__ dinv,
                         int* __restrict__ csr_src, float* __restrict__ csr_nrm, int n) {
  int e = blockIdx.x * blockDim.x + threadIdx.x;
  if (e >= E) return;
  unsigned int s = (unsigned int)ei[e];
  unsigned int d = (unsigned int)ei[(size_t)E + e];
  if (s >= (unsigned int)n || d >= (unsigned int)n) return;
  int pos = row_ptr[d] + atomicAdd(&cursor[d], 1);
  csr_src[pos] = (int)s;
  csr_nrm[pos] = dinv[s] * dinv[d];
}

// ---------------- GEMM: C[M,N] = A[M,K] @ Wt[N,Kpad]^T  (bf16 MFMA, full-N tile) ----------------
template<int BM, int BN, int TH, int WM, int WN, bool A_F32, bool ADD_BIAS, bool DO_RELU, bool OUT_BF16>
__global__ __launch_bounds__(TH)
void gemm_k(const void* __restrict__ Av, const unsigned short* __restrict__ Bt,
            const float* __restrict__ bias, void* __restrict__ Cv,
            int M, int N, int K, int Kpad) {
  constexpr int BK = 32;
  constexpr int WROWS = BM / WM, WCOLS = BN / WN;
  constexpr int FM = WROWS / 16, FN = WCOLS / 16;
  static_assert(WM * WN * 64 == TH, "wave grid");
  static_assert((BM * 8) % TH == 0 && (BN * 4) % TH == 0, "staging divisibility");

  __shared__ __align__(16) unsigned short Alds[BM * BK];
  __shared__ __align__(16) unsigned short Blds[BN * BK];

  const int tid = threadIdx.x;
  const int wid = tid >> 6, lane = tid & 63;
  const int wm = wid / WN, wn = wid % WN;
  const int gm = blockIdx.x * BM;
  const int kg = lane >> 4, lr = lane & 15;

  f32x4 acc[FM][FN] = {};

  const int nkt = Kpad / BK;
  for (int kt = 0; kt < nkt; ++kt) {
    const int k0 = kt * BK;
    // ---- stage A (with f32->bf16 conversion if needed), XOR slot swizzle ----
    if constexpr (A_F32) {
      const float* A = (const float*)Av;
      #pragma unroll
      for (int q0 = 0; q0 < BM * 8; q0 += TH) {
        int q = q0 + tid;
        int row = q >> 3, c4 = (q & 7) << 2;
        int grow = gm + row; if (grow > M - 1) grow = M - 1;
        const float* ap = A + (size_t)grow * K + k0 + c4;
        f32x4 v;
        if (k0 + c4 + 4 <= K) v = *(const f32x4*)ap;
        else {
          #pragma unroll
          for (int i = 0; i < 4; i++) v[i] = (k0 + c4 + i < K) ? ap[i] : 0.f;
        }
        short4v b;
        b[0] = (short)f2bf(v[0]); b[1] = (short)f2bf(v[1]);
        b[2] = (short)f2bf(v[2]); b[3] = (short)f2bf(v[3]);
        int slot = c4 >> 3;
        *(short4v*)(&Alds[row * 32 + ((slot ^ (row & 3)) << 3) + (c4 & 4)]) = b;
      }
    } else {
      const unsigned short* A = (const unsigned short*)Av;
      #pragma unroll
      for (int q0 = 0; q0 < BM * 4; q0 += TH) {
        int q = q0 + tid;
        int row = q >> 2, c8 = (q & 3) << 3;
        int grow = gm + row; if (grow > M - 1) grow = M - 1;
        short8 v = *(const short8*)(A + (size_t)grow * K + k0 + c8);
        *(short8*)(&Alds[row * 32 + (((c8 >> 3) ^ (row & 3)) << 3)]) = v;
      }
    }
    // ---- stage B (already bf16, pre-transposed, zero-padded) ----
    #pragma unroll
    for (int q0 = 0; q0 < BN * 4; q0 += TH) {
      int q = q0 + tid;
      int row = q >> 2, c8 = (q & 3) << 3;
      short8 v = *(const short8*)(Bt + (size_t)row * Kpad + k0 + c8);
      *(short8*)(&Blds[row * 32 + (((c8 >> 3) ^ (row & 3)) << 3)]) = v;
    }
    __syncthreads();
    // ---- fragments + MFMA ----
    short8 af[FM], bfr[FN];
    #pragma unroll
    for (int m = 0; m < FM; m++) {
      int r = wm * WROWS + m * 16 + lr;
      af[m] = *(const short8*)(&Alds[r * 32 + ((kg ^ (r & 3)) << 3)]);
    }
    #pragma unroll
    for (int n = 0; n < FN; n++) {
      int c = wn * WCOLS + n * 16 + lr;
      bfr[n] = *(const short8*)(&Blds[c * 32 + ((kg ^ (c & 3)) << 3)]);
    }
    #pragma unroll
    for (int m = 0; m < FM; m++)
      #pragma unroll
      for (int n = 0; n < FN; n++)
        acc[m][n] = __builtin_amdgcn_mfma_f32_16x16x32_bf16(af[m], bfr[n], acc[m][n], 0, 0, 0);
    __syncthreads();
  }
  // ---- epilogue: C/D layout col=lane&15, row=(lane>>4)*4+reg ----
  #pragma unroll
  for (int m = 0; m < FM; m++) {
    #pragma unroll
    for (int j = 0; j < 4; j++) {
      int grow = gm + wm * WROWS + m * 16 + kg * 4 + j;
      if (grow < M) {
        #pragma unroll
        for (int n = 0; n < FN; n++) {
          int gcol = wn * WCOLS + n * 16 + lr;
          float v = acc[m][n][j];
          if constexpr (ADD_BIAS) v += bias[gcol];
          if constexpr (DO_RELU) v = fmaxf(v, 0.f);
          if constexpr (OUT_BF16) ((unsigned short*)Cv)[(size_t)grow * N + gcol] = f2bf(v);
          else                    ((float*)Cv)[(size_t)grow * N + gcol] = v;
        }
      }
    }
  }
}

// ---------------- GCN scatter (gather-by-dst via CSR), fused bias/relu/combine ----------------
// MODE 0: out = w * val
// MODE 1: out = part + (1-w) * val
template<int F, bool DO_RELU, int MODE, bool OUT_BF16, bool PART_BF16>
__global__ __launch_bounds__(256)
void scatter_k(const float* __restrict__ h, const int* __restrict__ row_ptr,
               const int* __restrict__ csr_src, const float* __restrict__ csr_nrm,
               const float* __restrict__ dinv, const float* __restrict__ bias,
               const float* __restrict__ wptr, const void* __restrict__ part,
               void* __restrict__ outp, int n) {
  int node, f;
  if constexpr (F == 256) { node = blockIdx.x; f = threadIdx.x; }
  else { node = blockIdx.x * (256 / F) + (threadIdx.x / F); f = threadIdx.x % F; }
  if (node >= n) return;
  float di = dinv[node];
  float acc = di * di * h[(size_t)node * F + f];   // self-loop term
  const int e1 = row_ptr[node + 1];
  for (int e = row_ptr[node]; e < e1; ++e) {
    int s = csr_src[e];
    acc += csr_nrm[e] * h[(size_t)s * F + f];
  }
  float v = acc + bias[f];
  if constexpr (DO_RELU) v = fmaxf(v, 0.f);
  float w = *wptr;
  float r;
  size_t idx = (size_t)node * F + f;
  if constexpr (MODE == 0) r = w * v;
  else {
    float pv;
    if constexpr (PART_BF16) pv = bf2f(((const unsigned short*)part)[idx]);
    else pv = ((const float*)part)[idx];
    r = pv + (1.f - w) * v;
  }
  if constexpr (OUT_BF16) ((unsigned short*)outp)[idx] = f2bf(r);
  else                    ((float*)outp)[idx] = r;
}

// ---------------- host ----------------
extern "C" void kernel_launch(void* const* d_in, const int* in_sizes, int n_in,
                              void* d_out, int out_size, void* d_ws, size_t ws_size,
                              hipStream_t stream) {
  const float* gene  = (const float*)d_in[0];
  const float* img   = (const float*)d_in[1];
  const int* ei_ge = (const int*)d_in[2];   // integers arrive as int32
  const int* ei_sp = (const int*)d_in[3];
  const float* W_fc1 = (const float*)d_in[4];  const float* b_fc1 = (const float*)d_in[5];
  const float* W_fc2 = (const float*)d_in[6];  const float* b_fc2 = (const float*)d_in[7];
  const float* W_g11 = (const float*)d_in[8];  const float* b_g11 = (const float*)d_in[9];
  const float* W_g12 = (const float*)d_in[10]; const float* b_g12 = (const float*)d_in[11];
  const float* W_g21 = (const float*)d_in[12]; const float* b_g21 = (const float*)d_in[13];
  const float* W_g22 = (const float*)d_in[14]; const float* b_g22 = (const float*)d_in[15];
  const float* w1p   = (const float*)d_in[16];
  const float* w2p   = (const float*)d_in[17];

  const int Nn = 50000;
  const int E_ge = in_sizes[2] / 2;
  const int E_sp = in_sizes[3] / 2;

  char* ws = (char*)d_ws;
  size_t off = 0;
  auto alloc = [&](size_t bytes) -> void* {
    void* p = ws + off;
    off += (bytes + 255) & ~(size_t)255;
    return p;
  };

  unsigned short* Wt1  = (unsigned short*)alloc((size_t)512 * 3008 * 2);
  unsigned short* Wt2  = (unsigned short*)alloc((size_t)512 * 1024 * 2);
  unsigned short* Wt11 = (unsigned short*)alloc((size_t)256 * 512 * 2);
  unsigned short* Wt12 = (unsigned short*)alloc((size_t)256 * 512 * 2);
  unsigned short* Wt21 = (unsigned short*)alloc((size_t)64 * 256 * 2);
  unsigned short* Wt22 = (unsigned short*)alloc((size_t)64 * 256 * 2);
  int*   deg_sp  = (int*)alloc((size_t)Nn * 4);
  int*   deg_ge  = (int*)alloc((size_t)Nn * 4);
  float* dinv_sp = (float*)alloc((size_t)Nn * 4);
  float* dinv_ge = (float*)alloc((size_t)Nn * 4);
  int*   rp_sp   = (int*)alloc((size_t)(Nn + 1) * 4);
  int*   rp_ge   = (int*)alloc((size_t)(Nn + 1) * 4);
  int*   cursor  = (int*)alloc((size_t)Nn * 4);
  int*   csrc_sp = (int*)alloc((size_t)E_sp * 4);
  float* cnrm_sp = (float*)alloc((size_t)E_sp * 4);
  int*   csrc_ge = (int*)alloc((size_t)E_ge * 4);
  float* cnrm_ge = (float*)alloc((size_t)E_ge * 4);
  unsigned short* xbuf  = (unsigned short*)alloc((size_t)Nn * 512 * 2);  // x1 / x2, later Xc
  float* tmp   = (float*)alloc((size_t)Nn * 256 * 4);                    // GEMM out pre-scatter
  unsigned short* xpart = (unsigned short*)alloc((size_t)Nn * 256 * 2);  // bf16 part (256-col); fp32 part (64-col) fits too
  unsigned short* Xc = xbuf;                                             // combined x (bf16), aliases xbuf
  (void)ws_size; (void)n_in; (void)out_size;

  // 1. weight transposes (bf16, K zero-padded to 32)
  transpose_w<<<dim3(94, 16), 256, 0, stream>>>(W_fc1, Wt1, 3000, 512, 3008);
  transpose_w<<<dim3(32, 16), 256, 0, stream>>>(W_fc2, Wt2, 1024, 512, 1024);
  transpose_w<<<dim3(16, 8),  256, 0, stream>>>(W_g11, Wt11, 512, 256, 512);
  transpose_w<<<dim3(16, 8),  256, 0, stream>>>(W_g12, Wt12, 512, 256, 512);
  transpose_w<<<dim3(8, 2),   256, 0, stream>>>(W_g21, Wt21, 256, 64, 256);
  transpose_w<<<dim3(8, 2),   256, 0, stream>>>(W_g22, Wt22, 256, 64, 256);

  // 2. graph prep
  deg_init<<<CDIV(Nn, 256), 256, 0, stream>>>(deg_sp, deg_ge, Nn);
  deg_hist<<<CDIV(E_sp, 256), 256, 0, stream>>>(ei_sp, E_sp, deg_sp, Nn);
  deg_hist<<<CDIV(E_ge, 256), 256, 0, stream>>>(ei_ge, E_ge, deg_ge, Nn);
  dinv_k<<<CDIV(Nn, 256), 256, 0, stream>>>(deg_sp, dinv_sp, Nn);
  dinv_k<<<CDIV(Nn, 256), 256, 0, stream>>>(deg_ge, dinv_ge, Nn);
  scan_rowptr<<<1, 1024, 0, stream>>>(deg_sp, rp_sp, Nn);
  scan_rowptr<<<1, 1024, 0, stream>>>(deg_ge, rp_ge, Nn);
  zero_i32<<<CDIV(Nn, 256), 256, 0, stream>>>(cursor, Nn);
  csr_fill<<<CDIV(E_sp, 256), 256, 0, stream>>>(ei_sp, E_sp, rp_sp, cursor, dinv_sp, csrc_sp, cnrm_sp, Nn);
  zero_i32<<<CDIV(Nn, 256), 256, 0, stream>>>(cursor, Nn);
  csr_fill<<<CDIV(E_ge, 256), 256, 0, stream>>>(ei_ge, E_ge, rp_ge, cursor, dinv_ge, csrc_ge, cnrm_ge, Nn);

  // 3. x1 = relu(gene @ W_fc1 + b)  -> bf16
  gemm_k<64, 512, 512, 1, 8, true, true, true, true>
      <<<CDIV(Nn, 64), 512, 0, stream>>>(gene, Wt1, b_fc1, xbuf, Nn, 512, 3000, 3008);
  // 4. tmp = x1 @ W_g11  (fp32)
  gemm_k<64, 256, 256, 1, 4, false, false, false, false>
      <<<CDIV(Nn, 64), 256, 0, stream>>>(xbuf, Wt11, nullptr, tmp, Nn, 256, 512, 512);
  // 5. xpart = bf16( w1 * relu(gcn_scatter_sp(tmp) + b_g11) )
  scatter_k<256, true, 0, true, false><<<Nn, 256, 0, stream>>>(
      tmp, rp_sp, csrc_sp, cnrm_sp, dinv_sp, b_g11, w1p, nullptr, xpart, Nn);
  // 6. x2 = relu(img @ W_fc2 + b) -> bf16 (reuse xbuf)
  gemm_k<64, 512, 512, 1, 8, true, true, true, true>
      <<<CDIV(Nn, 64), 512, 0, stream>>>(img, Wt2, b_fc2, xbuf, Nn, 512, 1024, 1024);
  // 7. tmp = x2 @ W_g12
  gemm_k<64, 256, 256, 1, 4, false, false, false, false>
      <<<CDIV(Nn, 64), 256, 0, stream>>>(xbuf, Wt12, nullptr, tmp, Nn, 256, 512, 512);
  // 8. Xc = bf16(xpart + (1-w1) * relu(gcn_scatter_ge(tmp) + b_g12))   [Xc aliases xbuf; x2 no longer needed]
  scatter_k<256, true, 1, true, true><<<Nn, 256, 0, stream>>>(
      tmp, rp_ge, csrc_ge, cnrm_ge, dinv_ge, b_g12, w1p, xpart, Xc, Nn);
  // 9. tmp = Xc @ W_g21 (fp32, 64 cols)
  gemm_k<256, 64, 256, 4, 1, false, false, false, false>
      <<<CDIV(Nn, 256), 256, 0, stream>>>(Xc, Wt21, nullptr, tmp, Nn, 64, 256, 256);
  // 10. xpart(fp32) = w2 * (gcn_scatter_sp(tmp) + b_g21)
  scatter_k<64, false, 0, false, false><<<CDIV(Nn, 4), 256, 0, stream>>>(
      tmp, rp_sp, csrc_sp, cnrm_sp, dinv_sp, b_g21, w2p, nullptr, (float*)xpart, Nn);
  // 11. tmp = Xc @ W_g22
  gemm_k<256, 64, 256, 4, 1, false, false, false, false>
      <<<CDIV(Nn, 256), 256, 0, stream>>>(Xc, Wt22, nullptr, tmp, Nn, 64, 256, 256);
  // 12. d_out = xpart + (1-w2) * (gcn_scatter_ge(tmp) + b_g22)
  scatter_k<64, false, 1, false, false><<<CDIV(Nn, 4), 256, 0, stream>>>(
      tmp, rp_ge, csrc_ge, cnrm_ge, dinv_ge, b_g22, w2p, (float*)xpart, d_out, Nn);
}

// Round 3
// 1165.991 us; speedup vs baseline: 1.1634x; 1.1634x over previous
//
#include <hip/hip_runtime.h>
#include <stdint.h>

typedef __attribute__((ext_vector_type(4))) float f32x4;
typedef __attribute__((ext_vector_type(8))) short short8;

#define CDIV(a, b) (((a) + (b) - 1) / (b))

__device__ __forceinline__ unsigned short f2bf(float x) {
  union { float f; unsigned int u; } c; c.f = x;
  unsigned int r = c.u + 0x7FFFu + ((c.u >> 16) & 1u);   // round-to-nearest-even
  return (unsigned short)(r >> 16);
}
__device__ __forceinline__ float bf2f(unsigned short b) {
  union { unsigned int u; float f; } c; c.u = (unsigned int)b << 16; return c.f;
}

// async global->LDS, 16B per lane; LDS dest must be wave-uniform base + lane*16 (linear)
__device__ __forceinline__ void gl2lds16(const void* g, void* lds) {
  __builtin_amdgcn_global_load_lds(
      reinterpret_cast<const __attribute__((address_space(1))) unsigned int*>(
          reinterpret_cast<uintptr_t>(g)),
      reinterpret_cast<__attribute__((address_space(3))) unsigned int*>(
          reinterpret_cast<uintptr_t>(lds)),
      16, 0, 0);
}

// ---------------- weight transpose: W[K][N] f32 -> Wt[N][Kpad] bf16, zero-padded ----------------
__global__ void transpose_w(const float* __restrict__ W, unsigned short* __restrict__ Wt,
                            int K, int N, int Kpad) {
  __shared__ float tile[32][33];
  int kb = blockIdx.x * 32, nb = blockIdx.y * 32;
  int tx = threadIdx.x & 31, ty = threadIdx.x >> 5;  // 256 threads = 32x8
  for (int r = ty; r < 32; r += 8) {
    int k = kb + r, n = nb + tx;
    tile[r][tx] = (k < K && n < N) ? W[(size_t)k * N + n] : 0.f;
  }
  __syncthreads();
  for (int r = ty; r < 32; r += 8) {
    int n = nb + r, k = kb + tx;
    if (n < N && k < Kpad) Wt[(size_t)n * Kpad + k] = f2bf(tile[tx][r]);
  }
}

// ---------------- graph prep ----------------
__global__ void zero_i32(int* __restrict__ p, int n) {
  int i = blockIdx.x * blockDim.x + threadIdx.x;
  if (i < n) p[i] = 0;
}

__global__ void deg_init(int* __restrict__ a, int* __restrict__ b, int n) {
  int i = blockIdx.x * blockDim.x + threadIdx.x;
  if (i < n) { a[i] = 1; b[i] = 1; }   // self-loop
}

__global__ void deg_hist(const int* __restrict__ ei, int E, int* __restrict__ deg, int n) {
  int e = blockIdx.x * blockDim.x + threadIdx.x;
  if (e >= E) return;
  unsigned int d = (unsigned int)ei[(size_t)E + e];
  if (d < (unsigned int)n) atomicAdd(&deg[d], 1);
}

__global__ void dinv_k(const int* __restrict__ deg, float* __restrict__ dinv, int n) {
  int i = blockIdx.x * blockDim.x + threadIdx.x;
  if (i < n) dinv[i] = rsqrtf((float)deg[i]);
}

// exclusive scan of (deg-1) -> row_ptr[0..n], single block of 1024, shfl-based
__global__ void scan_rowptr(const int* __restrict__ deg, int* __restrict__ rp, int n) {
  __shared__ int wsum[16];
  __shared__ int carry_s;
  const int tid = threadIdx.x, lane = tid & 63, w = tid >> 6;
  if (tid == 0) carry_s = 0;
  __syncthreads();
  for (int base = 0; base < n; base += 1024) {
    int i = base + tid;
    int d = (i < n) ? (deg[i] - 1) : 0;
    int v = d;
    #pragma unroll
    for (int off = 1; off < 64; off <<= 1) {
      int t = __shfl_up(v, off, 64);
      if (lane >= off) v += t;
    }
    if (lane == 63) wsum[w] = v;
    __syncthreads();
    int carry = carry_s;
    if (w == 0) {
      int s = (lane < 16) ? wsum[lane] : 0;
      #pragma unroll
      for (int off = 1; off < 16; off <<= 1) {
        int t = __shfl_up(s, off, 64);
        if (lane >= off) s += t;
      }
      if (lane < 16) wsum[lane] = s;
    }
    __syncthreads();
    int woff = (w > 0) ? wsum[w - 1] : 0;
    if (i < n) rp[i] = carry + woff + v - d;
    if (tid == 0) carry_s = carry + wsum[15];
    __syncthreads();
  }
  if (threadIdx.x == 0) rp[n] = carry_s;
}

__global__ void csr_fill(const int* __restrict__ ei, int E,
                         const int* __restrict__ row_ptr, int* __restrict__ cursor,
                         const float* __restrict__ dinv,
                         int* __restrict__ csr_src, float* __restrict__ csr_nrm, int n) {
  int e = blockIdx.x * blockDim.x + threadIdx.x;
  if (e >= E) return;
  unsigned int s = (unsigned int)ei[e];
  unsigned int d = (unsigned int)ei[(size_t)E + e];
  if (s >= (unsigned int)n || d >= (unsigned int)n) return;
  int pos = row_ptr[d] + atomicAdd(&cursor[d], 1);
  csr_src[pos] = (int)s;
  csr_nrm[pos] = dinv[s] * dinv[d];
}

// ---------------- GEMM: C[M,N] = A[M,K] @ Wt[N,Kpad]^T  (bf16 MFMA, BK=64, B via global_load_lds)
// AMODE: 1 = A bf16 row-major (reg-staged), 2 = A f32 row-major (reg-staged + convert)
template<int BM, int BN, int TH, int WM, int WN, int AMODE, bool ADD_BIAS, bool DO_RELU, bool OUT_BF16>
__global__ __launch_bounds__(TH, 4)
void gemm2(const void* __restrict__ Av, const unsigned short* __restrict__ Bt,
           const float* __restrict__ bias, void* __restrict__ Cv,
           int M, int N, int K, int Kpad) {
  constexpr int BK = 64;
  constexpr int WROWS = BM / WM, WCOLS = BN / WN;
  constexpr int FM = WROWS / 16, FN = WCOLS / 16;
  static_assert(WM * WN * 64 == TH, "wave grid");
  static_assert((BM * 8) % TH == 0 && (BN * 8) % TH == 0, "staging divisibility");

  // LDS tiles: [rows][8 slots of 16B] (BK=64 bf16 = 128B/row). XOR slot swizzle on (r&7).
  __shared__ __align__(16) unsigned short Alds[BM * BK];
  __shared__ __align__(16) unsigned short Blds[BN * BK];

  const int tid = threadIdx.x;
  const int wid = tid >> 6, lane = tid & 63;
  const int wm = wid / WN, wn = wid % WN;
  const int gm = blockIdx.x * BM;
  const int kg = lane >> 4, lr = lane & 15;
  const int sx = lr & 7;   // frag-read slot XOR component (uniform per lane)

  f32x4 acc[FM][FN] = {};

  const int nkt = Kpad / BK;
  for (int kt = 0; kt < nkt; ++kt) {
    const int k0 = kt * BK;
    // ---- stage A (reg-staged, swizzled ds_write) ----
    #pragma unroll
    for (int q0 = 0; q0 < BM * 8; q0 += TH) {
      int q = q0 + tid;
      int r = q >> 3, s = q & 7;
      int grow = gm + r; if (grow > M - 1) grow = M - 1;
      int kbase = k0 + s * 8;
      short8 b;
      if constexpr (AMODE == 1) {
        const unsigned short* A = (const unsigned short*)Av;
        b = *(const short8*)(A + (size_t)grow * K + kbase);
      } else {
        const float* A = (const float*)Av;
        const float* ap = A + (size_t)grow * K + kbase;
        if (kbase + 8 <= K) {
          f32x4 v0 = *(const f32x4*)ap, v1 = *(const f32x4*)(ap + 4);
          b[0] = (short)f2bf(v0[0]); b[1] = (short)f2bf(v0[1]);
          b[2] = (short)f2bf(v0[2]); b[3] = (short)f2bf(v0[3]);
          b[4] = (short)f2bf(v1[0]); b[5] = (short)f2bf(v1[1]);
          b[6] = (short)f2bf(v1[2]); b[7] = (short)f2bf(v1[3]);
        } else {
          #pragma unroll
          for (int i = 0; i < 8; i++)
            b[i] = (kbase + i < K) ? (short)f2bf(ap[i]) : (short)0;
        }
      }
      *(short8*)(&Alds[(r * 8 + (s ^ (r & 7))) * 8]) = b;
    }
    // ---- stage B via global_load_lds: linear LDS dest, inverse-swizzled global source ----
    #pragma unroll
    for (int q0 = 0; q0 < BN * 8; q0 += TH) {
      int q = q0 + tid;
      int r = q >> 3, s = q & 7;
      gl2lds16(Bt + (size_t)r * Kpad + k0 + ((s ^ (r & 7)) * 8), &Blds[q * 8]);
    }
    __syncthreads();
    // ---- fragments + MFMA (2 K-slices of 32) ----
    #pragma unroll
    for (int ks = 0; ks < 2; ++ks) {
      const int k8 = ks * 4 + kg;
      short8 af[FM], bq[FN];
      #pragma unroll
      for (int m = 0; m < FM; m++) {
        int r = wm * WROWS + m * 16 + lr;
        af[m] = *(const short8*)(&Alds[(r * 8 + (k8 ^ sx)) * 8]);
      }
      #pragma unroll
      for (int n2 = 0; n2 < FN; n2++) {
        int c = wn * WCOLS + n2 * 16 + lr;
        bq[n2] = *(const short8*)(&Blds[(c * 8 + (k8 ^ sx)) * 8]);
      }
      #pragma unroll
      for (int m = 0; m < FM; m++)
        #pragma unroll
        for (int n2 = 0; n2 < FN; n2++)
          acc[m][n2] = __builtin_amdgcn_mfma_f32_16x16x32_bf16(af[m], bq[n2], acc[m][n2], 0, 0, 0);
    }
    __syncthreads();
  }
  // ---- epilogue: C/D layout col=lane&15, row=(lane>>4)*4+reg ----
  #pragma unroll
  for (int m = 0; m < FM; m++) {
    #pragma unroll
    for (int j = 0; j < 4; j++) {
      int grow = gm + wm * WROWS + m * 16 + kg * 4 + j;
      if (grow < M) {
        #pragma unroll
        for (int n2 = 0; n2 < FN; n2++) {
          int gcol = wn * WCOLS + n2 * 16 + lr;
          float v = acc[m][n2][j];
          if constexpr (ADD_BIAS) v += bias[gcol];
          if constexpr (DO_RELU) v = fmaxf(v, 0.f);
          if constexpr (OUT_BF16) ((unsigned short*)Cv)[(size_t)grow * N + gcol] = f2bf(v);
          else                    ((float*)Cv)[(size_t)grow * N + gcol] = v;
        }
      }
    }
  }
}

// ---------------- GCN scatter (gather-by-dst via CSR), h is bf16; fused bias/relu/combine ----
// MODE 0: out = w * val ;  MODE 1: out = part + (1-w) * val
template<int F, bool DO_RELU, int MODE, bool OUT_BF16, bool PART_BF16>
__global__ __launch_bounds__(256)
void scatter_k(const unsigned short* __restrict__ h, const int* __restrict__ row_ptr,
               const int* __restrict__ csr_src, const float* __restrict__ csr_nrm,
               const float* __restrict__ dinv, const float* __restrict__ bias,
               const float* __restrict__ wptr, const void* __restrict__ part,
               void* __restrict__ outp, int n) {
  int node, f;
  if constexpr (F == 256) { node = blockIdx.x; f = threadIdx.x; }
  else { node = blockIdx.x * (256 / F) + (threadIdx.x / F); f = threadIdx.x % F; }
  if (node >= n) return;
  float di = dinv[node];
  float acc = di * di * bf2f(h[(size_t)node * F + f]);   // self-loop term
  const int e1 = row_ptr[node + 1];
  for (int e = row_ptr[node]; e < e1; ++e) {
    int s = csr_src[e];
    acc += csr_nrm[e] * bf2f(h[(size_t)s * F + f]);
  }
  float v = acc + bias[f];
  if constexpr (DO_RELU) v = fmaxf(v, 0.f);
  float w = *wptr;
  float r;
  size_t idx = (size_t)node * F + f;
  if constexpr (MODE == 0) r = w * v;
  else {
    float pv;
    if constexpr (PART_BF16) pv = bf2f(((const unsigned short*)part)[idx]);
    else pv = ((const float*)part)[idx];
    r = pv + (1.f - w) * v;
  }
  if constexpr (OUT_BF16) ((unsigned short*)outp)[idx] = f2bf(r);
  else                    ((float*)outp)[idx] = r;
}

// ---------------- host ----------------
extern "C" void kernel_launch(void* const* d_in, const int* in_sizes, int n_in,
                              void* d_out, int out_size, void* d_ws, size_t ws_size,
                              hipStream_t stream) {
  const float* gene  = (const float*)d_in[0];
  const float* img   = (const float*)d_in[1];
  const int* ei_ge = (const int*)d_in[2];   // integers arrive as int32
  const int* ei_sp = (const int*)d_in[3];
  const float* W_fc1 = (const float*)d_in[4];  const float* b_fc1 = (const float*)d_in[5];
  const float* W_fc2 = (const float*)d_in[6];  const float* b_fc2 = (const float*)d_in[7];
  const float* W_g11 = (const float*)d_in[8];  const float* b_g11 = (const float*)d_in[9];
  const float* W_g12 = (const float*)d_in[10]; const float* b_g12 = (const float*)d_in[11];
  const float* W_g21 = (const float*)d_in[12]; const float* b_g21 = (const float*)d_in[13];
  const float* W_g22 = (const float*)d_in[14]; const float* b_g22 = (const float*)d_in[15];
  const float* w1p   = (const float*)d_in[16];
  const float* w2p   = (const float*)d_in[17];

  const int Nn = 50000;
  const int E_ge = in_sizes[2] / 2;
  const int E_sp = in_sizes[3] / 2;

  char* ws = (char*)d_ws;
  size_t off = 0;
  auto alloc = [&](size_t bytes) -> void* {
    void* p = ws + off;
    off += (bytes + 255) & ~(size_t)255;
    return p;
  };

  unsigned short* Wt1  = (unsigned short*)alloc((size_t)512 * 3008 * 2);
  unsigned short* Wt2  = (unsigned short*)alloc((size_t)512 * 1024 * 2);
  unsigned short* Wt11 = (unsigned short*)alloc((size_t)256 * 512 * 2);
  unsigned short* Wt12 = (unsigned short*)alloc((size_t)256 * 512 * 2);
  unsigned short* Wt21 = (unsigned short*)alloc((size_t)64 * 256 * 2);
  unsigned short* Wt22 = (unsigned short*)alloc((size_t)64 * 256 * 2);
  int*   deg_sp  = (int*)alloc((size_t)Nn * 4);
  int*   deg_ge  = (int*)alloc((size_t)Nn * 4);
  float* dinv_sp = (float*)alloc((size_t)Nn * 4);
  float* dinv_ge = (float*)alloc((size_t)Nn * 4);
  int*   rp_sp   = (int*)alloc((size_t)(Nn + 1) * 4);
  int*   rp_ge   = (int*)alloc((size_t)(Nn + 1) * 4);
  int*   cursor  = (int*)alloc((size_t)Nn * 4);
  int*   csrc_sp = (int*)alloc((size_t)E_sp * 4);
  float* cnrm_sp = (float*)alloc((size_t)E_sp * 4);
  int*   csrc_ge = (int*)alloc((size_t)E_ge * 4);
  float* cnrm_ge = (float*)alloc((size_t)E_ge * 4);
  unsigned short* xbuf  = (unsigned short*)alloc((size_t)Nn * 512 * 2);  // x1 / x2, later Xc
  unsigned short* tmp   = (unsigned short*)alloc((size_t)Nn * 256 * 2);  // GEMM out pre-scatter (bf16)
  unsigned short* xpart = (unsigned short*)alloc((size_t)Nn * 256 * 2);  // bf16 part; fp32 64-col part fits too
  unsigned short* Xc = xbuf;                                             // combined x (bf16), aliases xbuf
  (void)ws_size; (void)n_in; (void)out_size;

  // 1. weight transposes (bf16, K zero-padded)
  transpose_w<<<dim3(94, 16), 256, 0, stream>>>(W_fc1, Wt1, 3000, 512, 3008);
  transpose_w<<<dim3(32, 16), 256, 0, stream>>>(W_fc2, Wt2, 1024, 512, 1024);
  transpose_w<<<dim3(16, 8),  256, 0, stream>>>(W_g11, Wt11, 512, 256, 512);
  transpose_w<<<dim3(16, 8),  256, 0, stream>>>(W_g12, Wt12, 512, 256, 512);
  transpose_w<<<dim3(8, 2),   256, 0, stream>>>(W_g21, Wt21, 256, 64, 256);
  transpose_w<<<dim3(8, 2),   256, 0, stream>>>(W_g22, Wt22, 256, 64, 256);

  // 2. graph prep
  deg_init<<<CDIV(Nn, 256), 256, 0, stream>>>(deg_sp, deg_ge, Nn);
  deg_hist<<<CDIV(E_sp, 256), 256, 0, stream>>>(ei_sp, E_sp, deg_sp, Nn);
  deg_hist<<<CDIV(E_ge, 256), 256, 0, stream>>>(ei_ge, E_ge, deg_ge, Nn);
  dinv_k<<<CDIV(Nn, 256), 256, 0, stream>>>(deg_sp, dinv_sp, Nn);
  dinv_k<<<CDIV(Nn, 256), 256, 0, stream>>>(deg_ge, dinv_ge, Nn);
  scan_rowptr<<<1, 1024, 0, stream>>>(deg_sp, rp_sp, Nn);
  scan_rowptr<<<1, 1024, 0, stream>>>(deg_ge, rp_ge, Nn);
  zero_i32<<<CDIV(Nn, 256), 256, 0, stream>>>(cursor, Nn);
  csr_fill<<<CDIV(E_sp, 256), 256, 0, stream>>>(ei_sp, E_sp, rp_sp, cursor, dinv_sp, csrc_sp, cnrm_sp, Nn);
  zero_i32<<<CDIV(Nn, 256), 256, 0, stream>>>(cursor, Nn);
  csr_fill<<<CDIV(E_ge, 256), 256, 0, stream>>>(ei_ge, E_ge, rp_ge, cursor, dinv_ge, csrc_ge, cnrm_ge, Nn);

  // 3. x1 = relu(gene @ W_fc1 + b)  -> bf16
  gemm2<64, 512, 512, 1, 8, 2, true, true, true>
      <<<CDIV(Nn, 64), 512, 0, stream>>>(gene, Wt1, b_fc1, xbuf, Nn, 512, 3000, 3008);
  // 4. tmp = x1 @ W_g11  (bf16)
  gemm2<64, 256, 512, 1, 8, 1, false, false, true>
      <<<CDIV(Nn, 64), 512, 0, stream>>>(xbuf, Wt11, nullptr, tmp, Nn, 256, 512, 512);
  // 5. xpart = bf16( w1 * relu(gcn_scatter_sp(tmp) + b_g11) )
  scatter_k<256, true, 0, true, false><<<Nn, 256, 0, stream>>>(
      tmp, rp_sp, csrc_sp, cnrm_sp, dinv_sp, b_g11, w1p, nullptr, xpart, Nn);
  // 6. x2 = relu(img @ W_fc2 + b) -> bf16 (reuse xbuf)
  gemm2<64, 512, 512, 1, 8, 2, true, true, true>
      <<<CDIV(Nn, 64), 512, 0, stream>>>(img, Wt2, b_fc2, xbuf, Nn, 512, 1024, 1024);
  // 7. tmp = x2 @ W_g12
  gemm2<64, 256, 512, 1, 8, 1, false, false, true>
      <<<CDIV(Nn, 64), 512, 0, stream>>>(xbuf, Wt12, nullptr, tmp, Nn, 256, 512, 512);
  // 8. Xc = bf16(xpart + (1-w1) * relu(gcn_scatter_ge(tmp) + b_g12))   [Xc aliases xbuf]
  scatter_k<256, true, 1, true, true><<<Nn, 256, 0, stream>>>(
      tmp, rp_ge, csrc_ge, cnrm_ge, dinv_ge, b_g12, w1p, xpart, Xc, Nn);
  // 9. tmp = Xc @ W_g21 (bf16, 64 cols)
  gemm2<64, 64, 256, 1, 4, 1, false, false, true>
      <<<CDIV(Nn, 64), 256, 0, stream>>>(Xc, Wt21, nullptr, tmp, Nn, 64, 256, 256);
  // 10. xpart(fp32) = w2 * (gcn_scatter_sp(tmp) + b_g21)
  scatter_k<64, false, 0, false, false><<<CDIV(Nn, 4), 256, 0, stream>>>(
      tmp, rp_sp, csrc_sp, cnrm_sp, dinv_sp, b_g21, w2p, nullptr, (float*)xpart, Nn);
  // 11. tmp = Xc @ W_g22
  gemm2<64, 64, 256, 1, 4, 1, false, false, true>
      <<<CDIV(Nn, 64), 256, 0, stream>>>(Xc, Wt22, nullptr, tmp, Nn, 64, 256, 256);
  // 12. d_out = xpart + (1-w2) * (gcn_scatter_ge(tmp) + b_g22)
  scatter_k<64, false, 1, false, false><<<CDIV(Nn, 4), 256, 0, stream>>>(
      tmp, rp_ge, csrc_ge, cnrm_ge, dinv_ge, b_g22, w2p, (float*)xpart, d_out, Nn);
}